// Round 4
// baseline (312.674 us; speedup 1.0000x reference)
//
#include <hip/hip_runtime.h>
#include <math.h>

namespace {
constexpr int Bn = 32, Hn = 1024, Wn = 1024;
constexpr int STRIP = 4;                      // rows per block (divides Hn)
constexpr int GRID1 = Bn * Hn / STRIP;        // 8192 blocks -> 32 KB partials
constexpr float BWGT = 3.0f;
}

__device__ inline float4 vmax4(float4 a, float4 b) {
    return make_float4(fmaxf(a.x,b.x), fmaxf(a.y,b.y), fmaxf(a.z,b.z), fmaxf(a.w,b.w));
}
__device__ inline float4 vmin4(float4 a, float4 b) {
    return make_float4(fminf(a.x,b.x), fminf(a.y,b.y), fminf(a.z,b.z), fminf(a.w,b.w));
}

// Load-all-then-compute, sized to the gfx950 occupancy cliff: register tile
// kept <= 64 VGPRs (waves/SIMD halve at vgpr=64/128/256 — m69), pinned via
// __launch_bounds__(256,8). All 10 float4 loads per thread are issued
// back-to-back and genuinely fit in registers -> true MLP + 8 waves/SIMD TLP.
// Image borders use binary-target identities (0 for max, 1 for min) ==
// reduce_window's -inf/+inf init padding; exact (absmax 0.0 in R2/R3).
__global__ __launch_bounds__(256, 8) void bam_bce_rows(
    const float* __restrict__ pred, const float* __restrict__ tgt,
    float* __restrict__ partial)
{
    const int tid  = threadIdx.x;
    const int lane = tid & 63;
    const int wv   = tid >> 6;                // 4 waves per block
    const int x0   = tid << 2;
    const int rowBase = blockIdx.x * STRIP;   // strips never cross images
    const int y0 = rowBase & (Hn - 1);
    const bool vtop = (y0 != 0);              // row y0-1 exists (block-uniform)
    const bool vbot = (y0 != Hn - STRIP);     // row y0+STRIP exists
    const float* tb = tgt  + (size_t)rowBase * Wn;
    const float* pb = pred + (size_t)rowBase * Wn;

    // ---- issue ALL loads up-front: tv[r] = target row y0-1+r, r in 0..5 ----
    float4 tv[STRIP + 2];
    tv[0]         = make_float4(0.f, 0.f, 0.f, 0.f);
    tv[STRIP + 1] = make_float4(0.f, 0.f, 0.f, 0.f);
    if (vtop) tv[0] = *reinterpret_cast<const float4*>(tb - Wn + x0);
    #pragma unroll
    for (int r = 1; r <= STRIP; ++r)
        tv[r] = *reinterpret_cast<const float4*>(tb + (size_t)(r - 1) * Wn + x0);
    if (vbot) tv[STRIP + 1] = *reinterpret_cast<const float4*>(tb + (size_t)STRIP * Wn + x0);
    float4 pv[STRIP];
    #pragma unroll
    for (int r = 0; r < STRIP; ++r)
        pv[r] = *reinterpret_cast<const float4*>(pb + (size_t)r * Wn + x0);

    // ---- batched wave-edge exchange of raw target values (one barrier) ----
    __shared__ float eL[STRIP + 2][4];        // lane 0's column x0   per wave
    __shared__ float eR[STRIP + 2][4];        // lane 63's column x0+3 per wave
    if (lane == 0) {
        #pragma unroll
        for (int r = 0; r < STRIP + 2; ++r) eL[r][wv] = tv[r].x;
    }
    if (lane == 63) {
        #pragma unroll
        for (int r = 0; r < STRIP + 2; ++r) eR[r][wv] = tv[r].w;
    }
    __syncthreads();

    // nbv[r]: raw neighbor-column value for this lane's missing halo side.
    // Only meaningful in lanes 0 (left neighbor) and 63 (right neighbor).
    float nbv[STRIP + 2];
    #pragma unroll
    for (int r = 0; r < STRIP + 2; ++r) nbv[r] = 0.0f;
    if (lane == 0 && wv > 0) {
        #pragma unroll
        for (int r = 0; r < STRIP + 2; ++r) nbv[r] = eR[r][wv - 1];
    }
    if (lane == 63 && wv < 3) {
        #pragma unroll
        for (int r = 0; r < STRIP + 2; ++r) nbv[r] = eL[r][wv + 1];
    }

    float sum = 0.0f;
    #pragma unroll
    for (int i = 0; i < STRIP; ++i) {
        const bool useTop = (i > 0) || vtop;           // row r=i valid
        const bool useBot = (i < STRIP - 1) || vbot;   // row r=i+2 valid

        // vertical (3-row) max/min for own 4 columns + this lane's halo column
        float4 mx = tv[i + 1], mn = tv[i + 1];
        float  em = nbv[i + 1], en = nbv[i + 1];
        if (useTop) {
            mx = vmax4(mx, tv[i]); mn = vmin4(mn, tv[i]);
            em = fmaxf(em, nbv[i]); en = fminf(en, nbv[i]);
        }
        if (useBot) {
            mx = vmax4(mx, tv[i + 2]); mn = vmin4(mn, tv[i + 2]);
            em = fmaxf(em, nbv[i + 2]); en = fminf(en, nbv[i + 2]);
        }

        // horizontal neighbors: in-wave shuffle, patched at wave/image edges
        float Lmx = __shfl_up(mx.w, 1),  Lmn = __shfl_up(mn.w, 1);
        float Rmx = __shfl_down(mx.x, 1), Rmn = __shfl_down(mn.x, 1);
        if (lane == 0)  { Lmx = em; Lmn = en; }
        if (lane == 63) { Rmx = em; Rmn = en; }
        if (tid == 0)   { Lmx = 0.f; Lmn = 1.f; }      // image left border
        if (tid == 255) { Rmx = 0.f; Rmn = 1.f; }      // image right border

        const float4 t = tv[i + 1];
        const float4 p = pv[i];
        {
            const float wmx = fmaxf(fmaxf(Lmx, mx.x), mx.y);
            const float wmn = fminf(fminf(Lmn, mn.x), mn.y);
            const float w = (wmx > wmn) ? BWGT : 1.0f;
            const float x = (t.x != 0.0f) ? p.x : (1.0f - p.x);
            sum = fmaf(w, -__logf(x), sum);
        }
        {
            const float wmx = fmaxf(fmaxf(mx.x, mx.y), mx.z);
            const float wmn = fminf(fminf(mn.x, mn.y), mn.z);
            const float w = (wmx > wmn) ? BWGT : 1.0f;
            const float x = (t.y != 0.0f) ? p.y : (1.0f - p.y);
            sum = fmaf(w, -__logf(x), sum);
        }
        {
            const float wmx = fmaxf(fmaxf(mx.y, mx.z), mx.w);
            const float wmn = fminf(fminf(mn.y, mn.z), mn.w);
            const float w = (wmx > wmn) ? BWGT : 1.0f;
            const float x = (t.z != 0.0f) ? p.z : (1.0f - p.z);
            sum = fmaf(w, -__logf(x), sum);
        }
        {
            const float wmx = fmaxf(fmaxf(mx.z, mx.w), Rmx);
            const float wmn = fminf(fminf(mn.z, mn.w), Rmn);
            const float w = (wmx > wmn) ? BWGT : 1.0f;
            const float x = (t.w != 0.0f) ? p.w : (1.0f - p.w);
            sum = fmaf(w, -__logf(x), sum);
        }
    }

    // wave(64) shuffle reduce -> 4-wave LDS reduce -> one partial per block
    #pragma unroll
    for (int off = 32; off > 0; off >>= 1) sum += __shfl_down(sum, off);
    __shared__ float smem[4];
    if ((tid & 63) == 0) smem[tid >> 6] = sum;
    __syncthreads();
    if (tid == 0) partial[blockIdx.x] = (smem[0] + smem[1]) + (smem[2] + smem[3]);
}

__global__ __launch_bounds__(256) void bam_bce_reduce(
    const float* __restrict__ partial, float* __restrict__ out)
{
    const int tid = threadIdx.x;
    float s = 0.0f;
    for (int i = tid; i < GRID1; i += 256) s += partial[i];
    #pragma unroll
    for (int off = 32; off > 0; off >>= 1) s += __shfl_down(s, off);
    __shared__ float smem[4];
    if ((tid & 63) == 0) smem[tid >> 6] = s;
    __syncthreads();
    if (tid == 0) {
        const float invN = 1.0f / (float)((long long)Bn * Hn * Wn);  // 1/2^25, exact
        out[0] = ((smem[0] + smem[1]) + (smem[2] + smem[3])) * invN;
    }
}

extern "C" void kernel_launch(void* const* d_in, const int* in_sizes, int n_in,
                              void* d_out, int out_size, void* d_ws, size_t ws_size,
                              hipStream_t stream)
{
    const float* pred = (const float*)d_in[0];
    const float* tgt  = (const float*)d_in[1];
    float* partial = (float*)d_ws;            // 8192 floats = 32 KB, fully
                                              // overwritten each call (poison-safe)
    bam_bce_rows<<<GRID1, 256, 0, stream>>>(pred, tgt, partial);
    bam_bce_reduce<<<1, 256, 0, stream>>>(partial, (float*)d_out);
}

// Round 5
// 297.663 us; speedup vs baseline: 1.0504x; 1.0504x over previous
//
#include <hip/hip_runtime.h>
#include <math.h>

namespace {
constexpr int Bn = 32, Hn = 1024, Wn = 1024;
constexpr int STRIP = 8;                      // rows per block (divides Hn)
constexpr int GRID1 = Bn * Hn / STRIP;        // 4096 blocks -> 16 KB partials
constexpr float BWGT = 3.0f;
}

__device__ inline float4 vmax4(float4 a, float4 b) {
    return make_float4(fmaxf(a.x,b.x), fmaxf(a.y,b.y), fmaxf(a.z,b.z), fmaxf(a.w,b.w));
}
__device__ inline float4 vmin4(float4 a, float4 b) {
    return make_float4(fminf(a.x,b.x), fminf(a.y,b.y), fminf(a.z,b.z), fminf(a.w,b.w));
}

// Async global->LDS, 16 B per lane, dest = wave-uniform base + lane*16 (m104).
__device__ __forceinline__ void load_lds16(const float* g, float* l) {
    __builtin_amdgcn_global_load_lds(
        (const __attribute__((address_space(1))) void*)(g),
        (__attribute__((address_space(3))) void*)(l), 16, 0, 0);
}

// LDS-staged strip kernel: 10 target rows -> LDS via global_load_lds (no VGPR
// cost, R4's spill disaster avoided), 8 pred rows -> 32 VGPRs, ALL 18 memory
// ops issued back-to-back, ONE drain+barrier per block, then pure compute.
// Halo columns read straight from LDS (full row resident). Image borders use
// binary-target identities (0 for max, 1 for min) == reduce_window's
// -inf/+inf init padding; exact (absmax 0.0 in R2-R4).
__global__ __launch_bounds__(256, 4) void bam_bce_rows(
    const float* __restrict__ pred, const float* __restrict__ tgt,
    float* __restrict__ partial)
{
    __shared__ float tile[(STRIP + 2) * Wn];  // 40960 B exactly -> 4 blocks/CU

    const int tid  = threadIdx.x;
    const int lane = tid & 63;
    const int wv   = tid >> 6;                // 4 waves per block
    const int x0   = tid << 2;
    const int rowBase = blockIdx.x * STRIP;   // strips never cross images
    const int y0 = rowBase & (Hn - 1);
    const bool vtop = (y0 != 0);              // row y0-1 exists (block-uniform)
    const bool vbot = (y0 != Hn - STRIP);     // row y0+STRIP exists
    const float* tb = tgt  + (size_t)rowBase * Wn;
    const float* pb = pred + (size_t)rowBase * Wn;

    // ---- stage 10 target rows into LDS: wave wv covers cols [wv*256, +256) ----
    const int cbase = (wv << 8) + (lane << 2);
    #pragma unroll
    for (int r = 0; r < STRIP + 2; ++r) {
        if (r == 0 && !vtop) continue;            // block-uniform skips; the
        if (r == STRIP + 1 && !vbot) continue;    // unread rows stay garbage
        load_lds16(tb + (size_t)(r - 1) * Wn + cbase, &tile[r * Wn + (wv << 8)]);
    }
    // ---- pred rows straight to registers, same in-flight batch ----
    float4 pv[STRIP];
    #pragma unroll
    for (int r = 0; r < STRIP; ++r)
        pv[r] = *reinterpret_cast<const float4*>(pb + (size_t)r * Wn + x0);

    __syncthreads();   // single vmcnt(0) drain: tile + pred all resident now

    float sum = 0.0f;
    #pragma unroll
    for (int i = 0; i < STRIP; ++i) {
        const bool useTop = (i > 0) || vtop;           // LDS row i valid
        const bool useBot = (i < STRIP - 1) || vbot;   // LDS row i+2 valid

        // vertical (3-row) max/min for own 4 columns, from LDS
        const float4 b = *reinterpret_cast<const float4*>(&tile[(i + 1) * Wn + x0]);
        float4 mx = b, mn = b;
        if (useTop) {
            const float4 a = *reinterpret_cast<const float4*>(&tile[i * Wn + x0]);
            mx = vmax4(mx, a); mn = vmin4(mn, a);
        }
        if (useBot) {
            const float4 c = *reinterpret_cast<const float4*>(&tile[(i + 2) * Wn + x0]);
            mx = vmax4(mx, c); mn = vmin4(mn, c);
        }

        // halo column for wave-edge lanes, read directly from LDS (2 active
        // lanes, exec-masked). Image borders keep the 0/1 identities.
        float em = 0.0f, en = 1.0f;
        if ((lane == 0 && tid != 0) || (lane == 63 && tid != 255)) {
            const int hc = (lane == 0) ? (x0 - 1) : (x0 + 4);
            const float h1 = tile[(i + 1) * Wn + hc];
            em = h1; en = h1;
            if (useTop) { const float h0 = tile[i * Wn + hc];       em = fmaxf(em, h0); en = fminf(en, h0); }
            if (useBot) { const float h2 = tile[(i + 2) * Wn + hc]; em = fmaxf(em, h2); en = fminf(en, h2); }
        }

        // horizontal neighbors: in-wave shuffle, patched at wave/image edges
        float Lmx = __shfl_up(mx.w, 1),  Lmn = __shfl_up(mn.w, 1);
        float Rmx = __shfl_down(mx.x, 1), Rmn = __shfl_down(mn.x, 1);
        if (lane == 0)  { Lmx = em; Lmn = en; }
        if (lane == 63) { Rmx = em; Rmn = en; }

        const float4 t = b;                   // binary target, center row
        const float4 p = pv[i];
        {
            const float wmx = fmaxf(fmaxf(Lmx, mx.x), mx.y);
            const float wmn = fminf(fminf(Lmn, mn.x), mn.y);
            const float w = (wmx > wmn) ? BWGT : 1.0f;
            const float x = (t.x != 0.0f) ? p.x : (1.0f - p.x);
            sum = fmaf(w, -__logf(x), sum);
        }
        {
            const float wmx = fmaxf(fmaxf(mx.x, mx.y), mx.z);
            const float wmn = fminf(fminf(mn.x, mn.y), mn.z);
            const float w = (wmx > wmn) ? BWGT : 1.0f;
            const float x = (t.y != 0.0f) ? p.y : (1.0f - p.y);
            sum = fmaf(w, -__logf(x), sum);
        }
        {
            const float wmx = fmaxf(fmaxf(mx.y, mx.z), mx.w);
            const float wmn = fminf(fminf(mn.y, mn.z), mn.w);
            const float w = (wmx > wmn) ? BWGT : 1.0f;
            const float x = (t.z != 0.0f) ? p.z : (1.0f - p.z);
            sum = fmaf(w, -__logf(x), sum);
        }
        {
            const float wmx = fmaxf(fmaxf(mx.z, mx.w), Rmx);
            const float wmn = fminf(fminf(mn.z, mn.w), Rmn);
            const float w = (wmx > wmn) ? BWGT : 1.0f;
            const float x = (t.w != 0.0f) ? p.w : (1.0f - p.w);
            sum = fmaf(w, -__logf(x), sum);
        }
    }

    // wave(64) shuffle reduce -> cross-wave via reused tile[0..3] (keeps LDS
    // at exactly 40960 B so 4 blocks/CU still fit)
    #pragma unroll
    for (int off = 32; off > 0; off >>= 1) sum += __shfl_down(sum, off);
    __syncthreads();                          // all tile reads done before reuse
    if (lane == 0) tile[wv] = sum;
    __syncthreads();
    if (tid == 0) partial[blockIdx.x] = (tile[0] + tile[1]) + (tile[2] + tile[3]);
}

__global__ __launch_bounds__(256) void bam_bce_reduce(
    const float* __restrict__ partial, float* __restrict__ out)
{
    const int tid = threadIdx.x;
    float s = 0.0f;
    for (int i = tid; i < GRID1; i += 256) s += partial[i];
    #pragma unroll
    for (int off = 32; off > 0; off >>= 1) s += __shfl_down(s, off);
    __shared__ float smem[4];
    if ((tid & 63) == 0) smem[tid >> 6] = s;
    __syncthreads();
    if (tid == 0) {
        const float invN = 1.0f / (float)((long long)Bn * Hn * Wn);  // 1/2^25, exact
        out[0] = ((smem[0] + smem[1]) + (smem[2] + smem[3])) * invN;
    }
}

extern "C" void kernel_launch(void* const* d_in, const int* in_sizes, int n_in,
                              void* d_out, int out_size, void* d_ws, size_t ws_size,
                              hipStream_t stream)
{
    const float* pred = (const float*)d_in[0];
    const float* tgt  = (const float*)d_in[1];
    float* partial = (float*)d_ws;            // 4096 floats = 16 KB, fully
                                              // overwritten each call (poison-safe)
    bam_bce_rows<<<GRID1, 256, 0, stream>>>(pred, tgt, partial);
    bam_bce_reduce<<<1, 256, 0, stream>>>(partial, (float*)d_out);
}

// Round 6
// 282.647 us; speedup vs baseline: 1.1062x; 1.0531x over previous
//
#include <hip/hip_runtime.h>
#include <math.h>

namespace {
constexpr int Bn = 32, Hn = 1024, Wn = 1024;
constexpr int STRIP = 4;                      // rows per block (divides Hn)
constexpr int GRID1 = Bn * Hn / STRIP;        // 8192 blocks -> 32 KB partials
constexpr float BWGT = 3.0f;
constexpr int TROWS = STRIP + 2;              // 6 target rows incl. halo
// LDS layout: rows 0..5 = target (y0-1 .. y0+4), rows 6..9 = pred (y0..y0+3)
// Total 10*1024*4 = 40960 B exactly -> 4 blocks/CU.
}

__device__ inline float4 vmax4(float4 a, float4 b) {
    return make_float4(fmaxf(a.x,b.x), fmaxf(a.y,b.y), fmaxf(a.z,b.z), fmaxf(a.w,b.w));
}
__device__ inline float4 vmin4(float4 a, float4 b) {
    return make_float4(fminf(a.x,b.x), fminf(a.y,b.y), fminf(a.z,b.z), fminf(a.w,b.w));
}

// Async global->LDS, 16 B per lane, dest = wave-uniform base + lane*16 (m104).
__device__ __forceinline__ void load_lds16(const float* g, float* l) {
    __builtin_amdgcn_global_load_lds(
        (const __attribute__((address_space(1))) void*)(g),
        (__attribute__((address_space(3))) void*)(l), 16, 0, 0);
}

// ALL staging via global_load_lds (zero VGPR cost -> nothing to spill; the
// R3/R4/R5 spill trap is structurally impossible). 10 wave-instructions per
// wave issued back-to-back, ONE drain+barrier, then pure LDS compute.
// Image borders use binary-target identities (0 for max, 1 for min) ==
// reduce_window's -inf/+inf init padding; exact (absmax 0.0 in R2-R5).
__global__ __launch_bounds__(256) void bam_bce_rows(
    const float* __restrict__ pred, const float* __restrict__ tgt,
    float* __restrict__ partial)
{
    __shared__ float tile[(TROWS + STRIP) * Wn];   // 40960 B exactly

    const int tid  = threadIdx.x;
    const int lane = tid & 63;
    const int wv   = tid >> 6;                // 4 waves per block
    const int x0   = tid << 2;
    const int rowBase = blockIdx.x * STRIP;   // strips never cross images
    const int y0 = rowBase & (Hn - 1);
    const bool vtop = (y0 != 0);              // row y0-1 exists (block-uniform)
    const bool vbot = (y0 != Hn - STRIP);     // row y0+STRIP exists
    const float* tb = tgt  + (size_t)rowBase * Wn;
    const float* pb = pred + (size_t)rowBase * Wn;

    // ---- stage 6 target rows + 4 pred rows into LDS, all in flight at once;
    //      wave wv covers columns [wv*256, wv*256+256) of each row ----
    const int cb = (wv << 8) + (lane << 2);   // this lane's source column
    const int db = (wv << 8);                 // wave-uniform LDS dest base
    #pragma unroll
    for (int r = 0; r < TROWS; ++r) {
        if (r == 0 && !vtop) continue;            // block-uniform skips; the
        if (r == TROWS - 1 && !vbot) continue;    // unread rows stay garbage
        load_lds16(tb + (size_t)(r - 1) * Wn + cb, &tile[r * Wn + db]);
    }
    #pragma unroll
    for (int r = 0; r < STRIP; ++r)
        load_lds16(pb + (size_t)r * Wn + cb, &tile[(TROWS + r) * Wn + db]);

    __syncthreads();   // single vmcnt(0) drain: everything resident now

    float sum = 0.0f;
    #pragma unroll
    for (int i = 0; i < STRIP; ++i) {
        const bool useTop = (i > 0) || vtop;           // LDS row i valid
        const bool useBot = (i < STRIP - 1) || vbot;   // LDS row i+2 valid

        // vertical (3-row) max/min for own 4 columns, from LDS
        const float4 b = *reinterpret_cast<const float4*>(&tile[(i + 1) * Wn + x0]);
        float4 mx = b, mn = b;
        if (useTop) {
            const float4 a = *reinterpret_cast<const float4*>(&tile[i * Wn + x0]);
            mx = vmax4(mx, a); mn = vmin4(mn, a);
        }
        if (useBot) {
            const float4 c = *reinterpret_cast<const float4*>(&tile[(i + 2) * Wn + x0]);
            mx = vmax4(mx, c); mn = vmin4(mn, c);
        }

        // halo column for wave-edge lanes, read directly from LDS (2 active
        // lanes, exec-masked). Image borders keep the 0/1 identities.
        float em = 0.0f, en = 1.0f;
        if ((lane == 0 && tid != 0) || (lane == 63 && tid != 255)) {
            const int hc = (lane == 0) ? (x0 - 1) : (x0 + 4);
            const float h1 = tile[(i + 1) * Wn + hc];
            em = h1; en = h1;
            if (useTop) { const float h0 = tile[i * Wn + hc];       em = fmaxf(em, h0); en = fminf(en, h0); }
            if (useBot) { const float h2 = tile[(i + 2) * Wn + hc]; em = fmaxf(em, h2); en = fminf(en, h2); }
        }

        // horizontal neighbors: in-wave shuffle, patched at wave/image edges
        float Lmx = __shfl_up(mx.w, 1),  Lmn = __shfl_up(mn.w, 1);
        float Rmx = __shfl_down(mx.x, 1), Rmn = __shfl_down(mn.x, 1);
        if (lane == 0)  { Lmx = em; Lmn = en; }
        if (lane == 63) { Rmx = em; Rmn = en; }

        const float4 t = b;                   // binary target, center row
        const float4 p = *reinterpret_cast<const float4*>(&tile[(TROWS + i) * Wn + x0]);
        {
            const float wmx = fmaxf(fmaxf(Lmx, mx.x), mx.y);
            const float wmn = fminf(fminf(Lmn, mn.x), mn.y);
            const float w = (wmx > wmn) ? BWGT : 1.0f;
            const float x = (t.x != 0.0f) ? p.x : (1.0f - p.x);
            sum = fmaf(w, -__logf(x), sum);
        }
        {
            const float wmx = fmaxf(fmaxf(mx.x, mx.y), mx.z);
            const float wmn = fminf(fminf(mn.x, mn.y), mn.z);
            const float w = (wmx > wmn) ? BWGT : 1.0f;
            const float x = (t.y != 0.0f) ? p.y : (1.0f - p.y);
            sum = fmaf(w, -__logf(x), sum);
        }
        {
            const float wmx = fmaxf(fmaxf(mx.y, mx.z), mx.w);
            const float wmn = fminf(fminf(mn.y, mn.z), mn.w);
            const float w = (wmx > wmn) ? BWGT : 1.0f;
            const float x = (t.z != 0.0f) ? p.z : (1.0f - p.z);
            sum = fmaf(w, -__logf(x), sum);
        }
        {
            const float wmx = fmaxf(fmaxf(mx.z, mx.w), Rmx);
            const float wmn = fminf(fminf(mn.z, mn.w), Rmn);
            const float w = (wmx > wmn) ? BWGT : 1.0f;
            const float x = (t.w != 0.0f) ? p.w : (1.0f - p.w);
            sum = fmaf(w, -__logf(x), sum);
        }
    }

    // wave(64) shuffle reduce -> cross-wave via reused tile[0..3]
    #pragma unroll
    for (int off = 32; off > 0; off >>= 1) sum += __shfl_down(sum, off);
    __syncthreads();                          // all tile reads done before reuse
    if (lane == 0) tile[wv] = sum;
    __syncthreads();
    if (tid == 0) partial[blockIdx.x] = (tile[0] + tile[1]) + (tile[2] + tile[3]);
}

__global__ __launch_bounds__(256) void bam_bce_reduce(
    const float* __restrict__ partial, float* __restrict__ out)
{
    const int tid = threadIdx.x;
    float s = 0.0f;
    for (int i = tid; i < GRID1; i += 256) s += partial[i];
    #pragma unroll
    for (int off = 32; off > 0; off >>= 1) s += __shfl_down(s, off);
    __shared__ float smem[4];
    if ((tid & 63) == 0) smem[tid >> 6] = s;
    __syncthreads();
    if (tid == 0) {
        const float invN = 1.0f / (float)((long long)Bn * Hn * Wn);  // 1/2^25, exact
        out[0] = ((smem[0] + smem[1]) + (smem[2] + smem[3])) * invN;
    }
}

extern "C" void kernel_launch(void* const* d_in, const int* in_sizes, int n_in,
                              void* d_out, int out_size, void* d_ws, size_t ws_size,
                              hipStream_t stream)
{
    const float* pred = (const float*)d_in[0];
    const float* tgt  = (const float*)d_in[1];
    float* partial = (float*)d_ws;            // 8192 floats = 32 KB, fully
                                              // overwritten each call (poison-safe)
    bam_bce_rows<<<GRID1, 256, 0, stream>>>(pred, tgt, partial);
    bam_bce_reduce<<<1, 256, 0, stream>>>(partial, (float*)d_out);
}

// Round 7
// 282.043 us; speedup vs baseline: 1.1086x; 1.0021x over previous
//
#include <hip/hip_runtime.h>
#include <math.h>

namespace {
constexpr int Bn = 32, Hn = 1024, Wn = 1024;
constexpr int STRIP = 4;                      // rows per block/strip
constexpr int GRID1 = Bn * Hn / STRIP;        // 8192 blocks -> 32 KB partials
constexpr int SPI = Hn / STRIP;               // 256 strips per image
constexpr float BWGT = 3.0f;
}

__device__ inline float4 vmax4(float4 a, float4 b) {
    return make_float4(fmaxf(a.x,b.x), fmaxf(a.y,b.y), fmaxf(a.z,b.z), fmaxf(a.w,b.w));
}
__device__ inline float4 vmin4(float4 a, float4 b) {
    return make_float4(fminf(a.x,b.x), fminf(a.y,b.y), fminf(a.z,b.z), fminf(a.w,b.w));
}

// Wave-autonomous register tile: each wave owns 4 rows x 256 cols. Plain
// float4 loads (the only staging path that has sustained >3 TB/s on this
// workload: R1/R4 evidence; global_load_lds bulk streaming capped ~5 B/cy/CU
// in R6). Tile = 46 data VGPRs -- under the 64-reg cliff, no launch_bounds
// forcing (R4's spill lesson), no hot-path LDS/barriers. Halo columns via
// exec-masked single-lane scalar loads (1 cache line each). Image borders
// use binary-target identities (0 for max, 1 for min) == reduce_window's
// -inf/+inf init padding; exact (absmax 0.0 in R2-R6).
__global__ void bam_bce_rows(
    const float* __restrict__ pred, const float* __restrict__ tgt,
    float* __restrict__ partial)
{
    const int tid  = threadIdx.x;
    const int lane = tid & 63;
    const int wv   = tid >> 6;                 // 4 waves = 4 column segments
    // XCD-contiguous swizzle: XCD x gets strips [1024x, 1024x+1024) = 4 images
    const int strip = ((blockIdx.x & 7) << 10) + (blockIdx.x >> 3);
    const int sIm = strip & (SPI - 1);         // strip index within its image
    const int y0  = sIm * STRIP;
    const bool vtop = (y0 != 0);
    const bool vbot = (y0 != Hn - STRIP);
    const int cbase = wv << 8;                 // wave's column base
    const int x0 = cbase + (lane << 2);        // lane's first column
    const float* tb = tgt  + (size_t)strip * STRIP * Wn;   // row y0, col 0
    const float* pb = pred + (size_t)strip * STRIP * Wn;

    // ---- all loads issued back-to-back: 6 tgt rows + 4 pred rows (float4)
    //      + up to 12 single-lane halo scalars ----
    float4 tv[STRIP + 2];
    tv[0]         = make_float4(0.f, 0.f, 0.f, 0.f);
    tv[STRIP + 1] = make_float4(0.f, 0.f, 0.f, 0.f);
    if (vtop) tv[0] = *reinterpret_cast<const float4*>(tb - Wn + x0);
    #pragma unroll
    for (int r = 1; r <= STRIP; ++r)
        tv[r] = *reinterpret_cast<const float4*>(tb + (size_t)(r - 1) * Wn + x0);
    if (vbot) tv[STRIP + 1] = *reinterpret_cast<const float4*>(tb + (size_t)STRIP * Wn + x0);

    float4 pv[STRIP];
    #pragma unroll
    for (int r = 0; r < STRIP; ++r)
        pv[r] = *reinterpret_cast<const float4*>(pb + (size_t)r * Wn + x0);

    // halo column values, rows y0-1..y0+4: lane 0 reads col cbase-1 (unless
    // image-left), lane 63 reads col cbase+256 (unless image-right). Only
    // 1-2 lanes active -> 1 cache line per row. Values only consumed in
    // those lanes; elsewhere garbage/unused.
    float hv[STRIP + 2];
    const bool doL = (lane == 0  && wv > 0);
    const bool doR = (lane == 63 && wv < 3);
    const int  hc  = doL ? (cbase - 1) : (cbase + 256);
    #pragma unroll
    for (int r = 0; r < STRIP + 2; ++r) hv[r] = 0.0f;
    if (doL || doR) {
        if (vtop) hv[0] = tb[-Wn + hc];
        #pragma unroll
        for (int r = 1; r <= STRIP; ++r) hv[r] = tb[(size_t)(r - 1) * Wn + hc];
        if (vbot) hv[STRIP + 1] = tb[(size_t)STRIP * Wn + hc];
    }

    float sum = 0.0f;
    #pragma unroll
    for (int i = 0; i < STRIP; ++i) {
        const bool useTop = (i > 0) || vtop;
        const bool useBot = (i < STRIP - 1) || vbot;

        // vertical 3-row max/min, all from registers
        float4 mx = tv[i + 1], mn = tv[i + 1];
        float  em = hv[i + 1], en = hv[i + 1];
        if (useTop) {
            mx = vmax4(mx, tv[i]); mn = vmin4(mn, tv[i]);
            em = fmaxf(em, hv[i]); en = fminf(en, hv[i]);
        }
        if (useBot) {
            mx = vmax4(mx, tv[i + 2]); mn = vmin4(mn, tv[i + 2]);
            em = fmaxf(em, hv[i + 2]); en = fminf(en, hv[i + 2]);
        }
        // image borders: max-identity 0 / min-identity 1
        if (tid == 0)   { em = 0.0f; en = 1.0f; }
        if (tid == 255) { em = 0.0f; en = 1.0f; }

        // horizontal neighbors: in-wave shuffle, patched at segment edges
        float Lmx = __shfl_up(mx.w, 1),  Lmn = __shfl_up(mn.w, 1);
        float Rmx = __shfl_down(mx.x, 1), Rmn = __shfl_down(mn.x, 1);
        if (lane == 0)  { Lmx = em; Lmn = en; }
        if (lane == 63) { Rmx = em; Rmn = en; }

        const float4 t = tv[i + 1];
        const float4 p = pv[i];
        {
            const float wmx = fmaxf(fmaxf(Lmx, mx.x), mx.y);
            const float wmn = fminf(fminf(Lmn, mn.x), mn.y);
            const float w = (wmx > wmn) ? BWGT : 1.0f;
            const float x = (t.x != 0.0f) ? p.x : (1.0f - p.x);
            sum = fmaf(w, -__logf(x), sum);
        }
        {
            const float wmx = fmaxf(fmaxf(mx.x, mx.y), mx.z);
            const float wmn = fminf(fminf(mn.x, mn.y), mn.z);
            const float w = (wmx > wmn) ? BWGT : 1.0f;
            const float x = (t.y != 0.0f) ? p.y : (1.0f - p.y);
            sum = fmaf(w, -__logf(x), sum);
        }
        {
            const float wmx = fmaxf(fmaxf(mx.y, mx.z), mx.w);
            const float wmn = fminf(fminf(mn.y, mn.z), mn.w);
            const float w = (wmx > wmn) ? BWGT : 1.0f;
            const float x = (t.z != 0.0f) ? p.z : (1.0f - p.z);
            sum = fmaf(w, -__logf(x), sum);
        }
        {
            const float wmx = fmaxf(fmaxf(mx.z, mx.w), Rmx);
            const float wmn = fminf(fminf(mn.z, mn.w), Rmn);
            const float w = (wmx > wmn) ? BWGT : 1.0f;
            const float x = (t.w != 0.0f) ? p.w : (1.0f - p.w);
            sum = fmaf(w, -__logf(x), sum);
        }
    }

    // wave(64) shuffle reduce -> tiny LDS cross-wave reduce (cold path)
    #pragma unroll
    for (int off = 32; off > 0; off >>= 1) sum += __shfl_down(sum, off);
    __shared__ float smem[4];
    if (lane == 0) smem[wv] = sum;
    __syncthreads();
    if (tid == 0) partial[blockIdx.x] = (smem[0] + smem[1]) + (smem[2] + smem[3]);
}

__global__ __launch_bounds__(256) void bam_bce_reduce(
    const float* __restrict__ partial, float* __restrict__ out)
{
    const int tid = threadIdx.x;
    float s = 0.0f;
    for (int i = tid; i < GRID1; i += 256) s += partial[i];
    #pragma unroll
    for (int off = 32; off > 0; off >>= 1) s += __shfl_down(s, off);
    __shared__ float smem[4];
    if ((tid & 63) == 0) smem[tid >> 6] = s;
    __syncthreads();
    if (tid == 0) {
        const float invN = 1.0f / (float)((long long)Bn * Hn * Wn);  // 1/2^25, exact
        out[0] = ((smem[0] + smem[1]) + (smem[2] + smem[3])) * invN;
    }
}

extern "C" void kernel_launch(void* const* d_in, const int* in_sizes, int n_in,
                              void* d_out, int out_size, void* d_ws, size_t ws_size,
                              hipStream_t stream)
{
    const float* pred = (const float*)d_in[0];
    const float* tgt  = (const float*)d_in[1];
    float* partial = (float*)d_ws;            // 8192 floats = 32 KB, fully
                                              // overwritten each call (poison-safe)
    bam_bce_rows<<<GRID1, 256, 0, stream>>>(pred, tgt, partial);
    bam_bce_reduce<<<1, 256, 0, stream>>>(partial, (float*)d_out);
}

// Round 8
// 280.870 us; speedup vs baseline: 1.1132x; 1.0042x over previous
//
#include <hip/hip_runtime.h>
#include <math.h>

namespace {
constexpr int Bn = 32, Hn = 1024, Wn = 1024;
constexpr int STRIP = 4;                      // rows per block/strip
constexpr int GRID1 = Bn * Hn / STRIP;        // 8192 blocks -> 32 KB partials
constexpr int SPI = Hn / STRIP;               // 256 strips per image
constexpr float BWGT = 3.0f;
}

__device__ inline float4 vmax4(float4 a, float4 b) {
    return make_float4(fmaxf(a.x,b.x), fmaxf(a.y,b.y), fmaxf(a.z,b.z), fmaxf(a.w,b.w));
}
__device__ inline float4 vmin4(float4 a, float4 b) {
    return make_float4(fminf(a.x,b.x), fminf(a.y,b.y), fminf(a.z,b.z), fminf(a.w,b.w));
}

// R7 structure + __launch_bounds__(256, 2): the tile needs ~58 VGPRs
// (tv 24 + pv 16 + hv 6 + addr/temps); every prior round the allocator's
// occupancy heuristic gave fewer (16/32/48) and serialized the loads into
// latency chains (~5.6 B/cy/CU ingest), or a forced cap (256,8)=64 spilled.
// (256,2) raises the ceiling to 256 regs so all 22 loads can be genuinely
// in flight (10 KB/wave outstanding; 16 waves/CU = 160 KB/CU >> Little's-law
// minimum). Image borders use binary-target identities (0 for max, 1 for
// min) == reduce_window's -inf/+inf init padding; exact (absmax 0.0 R2-R7).
__global__ __launch_bounds__(256, 2) void bam_bce_rows(
    const float* __restrict__ pred, const float* __restrict__ tgt,
    float* __restrict__ partial)
{
    const int tid  = threadIdx.x;
    const int lane = tid & 63;
    const int wv   = tid >> 6;                 // 4 waves = 4 column segments
    // XCD-contiguous swizzle: XCD x gets strips [1024x, 1024x+1024) = 4 images
    const int strip = ((blockIdx.x & 7) << 10) + (blockIdx.x >> 3);
    const int sIm = strip & (SPI - 1);         // strip index within its image
    const int y0  = sIm * STRIP;
    const bool vtop = (y0 != 0);
    const bool vbot = (y0 != Hn - STRIP);
    const int cbase = wv << 8;                 // wave's column base
    const int x0 = cbase + (lane << 2);        // lane's first column
    const float* tb = tgt  + (size_t)strip * STRIP * Wn;   // row y0, col 0
    const float* pb = pred + (size_t)strip * STRIP * Wn;

    // ---- all loads issued back-to-back: 6 tgt rows + 4 pred rows (float4)
    //      + up to 12 single-lane halo scalars ----
    float4 tv[STRIP + 2];
    tv[0]         = make_float4(0.f, 0.f, 0.f, 0.f);
    tv[STRIP + 1] = make_float4(0.f, 0.f, 0.f, 0.f);
    if (vtop) tv[0] = *reinterpret_cast<const float4*>(tb - Wn + x0);
    #pragma unroll
    for (int r = 1; r <= STRIP; ++r)
        tv[r] = *reinterpret_cast<const float4*>(tb + (size_t)(r - 1) * Wn + x0);
    if (vbot) tv[STRIP + 1] = *reinterpret_cast<const float4*>(tb + (size_t)STRIP * Wn + x0);

    float4 pv[STRIP];
    #pragma unroll
    for (int r = 0; r < STRIP; ++r)
        pv[r] = *reinterpret_cast<const float4*>(pb + (size_t)r * Wn + x0);

    // halo column values, rows y0-1..y0+4: lane 0 reads col cbase-1 (unless
    // image-left), lane 63 reads col cbase+256 (unless image-right). Only
    // 1-2 lanes active -> 1 cache line per row. Values only consumed in
    // those lanes; elsewhere garbage/unused.
    float hv[STRIP + 2];
    const bool doL = (lane == 0  && wv > 0);
    const bool doR = (lane == 63 && wv < 3);
    const int  hc  = doL ? (cbase - 1) : (cbase + 256);
    #pragma unroll
    for (int r = 0; r < STRIP + 2; ++r) hv[r] = 0.0f;
    if (doL || doR) {
        if (vtop) hv[0] = tb[-Wn + hc];
        #pragma unroll
        for (int r = 1; r <= STRIP; ++r) hv[r] = tb[(size_t)(r - 1) * Wn + hc];
        if (vbot) hv[STRIP + 1] = tb[(size_t)STRIP * Wn + hc];
    }

    float sum = 0.0f;
    #pragma unroll
    for (int i = 0; i < STRIP; ++i) {
        const bool useTop = (i > 0) || vtop;
        const bool useBot = (i < STRIP - 1) || vbot;

        // vertical 3-row max/min, all from registers
        float4 mx = tv[i + 1], mn = tv[i + 1];
        float  em = hv[i + 1], en = hv[i + 1];
        if (useTop) {
            mx = vmax4(mx, tv[i]); mn = vmin4(mn, tv[i]);
            em = fmaxf(em, hv[i]); en = fminf(en, hv[i]);
        }
        if (useBot) {
            mx = vmax4(mx, tv[i + 2]); mn = vmin4(mn, tv[i + 2]);
            em = fmaxf(em, hv[i + 2]); en = fminf(en, hv[i + 2]);
        }
        // image borders: max-identity 0 / min-identity 1
        if (tid == 0)   { em = 0.0f; en = 1.0f; }
        if (tid == 255) { em = 0.0f; en = 1.0f; }

        // horizontal neighbors: in-wave shuffle, patched at segment edges
        float Lmx = __shfl_up(mx.w, 1),  Lmn = __shfl_up(mn.w, 1);
        float Rmx = __shfl_down(mx.x, 1), Rmn = __shfl_down(mn.x, 1);
        if (lane == 0)  { Lmx = em; Lmn = en; }
        if (lane == 63) { Rmx = em; Rmn = en; }

        const float4 t = tv[i + 1];
        const float4 p = pv[i];
        {
            const float wmx = fmaxf(fmaxf(Lmx, mx.x), mx.y);
            const float wmn = fminf(fminf(Lmn, mn.x), mn.y);
            const float w = (wmx > wmn) ? BWGT : 1.0f;
            const float x = (t.x != 0.0f) ? p.x : (1.0f - p.x);
            sum = fmaf(w, -__logf(x), sum);
        }
        {
            const float wmx = fmaxf(fmaxf(mx.x, mx.y), mx.z);
            const float wmn = fminf(fminf(mn.x, mn.y), mn.z);
            const float w = (wmx > wmn) ? BWGT : 1.0f;
            const float x = (t.y != 0.0f) ? p.y : (1.0f - p.y);
            sum = fmaf(w, -__logf(x), sum);
        }
        {
            const float wmx = fmaxf(fmaxf(mx.y, mx.z), mx.w);
            const float wmn = fminf(fminf(mn.y, mn.z), mn.w);
            const float w = (wmx > wmn) ? BWGT : 1.0f;
            const float x = (t.z != 0.0f) ? p.z : (1.0f - p.z);
            sum = fmaf(w, -__logf(x), sum);
        }
        {
            const float wmx = fmaxf(fmaxf(mx.z, mx.w), Rmx);
            const float wmn = fminf(fminf(mn.z, mn.w), Rmn);
            const float w = (wmx > wmn) ? BWGT : 1.0f;
            const float x = (t.w != 0.0f) ? p.w : (1.0f - p.w);
            sum = fmaf(w, -__logf(x), sum);
        }
    }

    // wave(64) shuffle reduce -> tiny LDS cross-wave reduce (cold path)
    #pragma unroll
    for (int off = 32; off > 0; off >>= 1) sum += __shfl_down(sum, off);
    __shared__ float smem[4];
    if (lane == 0) smem[wv] = sum;
    __syncthreads();
    if (tid == 0) partial[blockIdx.x] = (smem[0] + smem[1]) + (smem[2] + smem[3]);
}

__global__ __launch_bounds__(256) void bam_bce_reduce(
    const float* __restrict__ partial, float* __restrict__ out)
{
    const int tid = threadIdx.x;
    float s = 0.0f;
    for (int i = tid; i < GRID1; i += 256) s += partial[i];
    #pragma unroll
    for (int off = 32; off > 0; off >>= 1) s += __shfl_down(s, off);
    __shared__ float smem[4];
    if ((tid & 63) == 0) smem[tid >> 6] = s;
    __syncthreads();
    if (tid == 0) {
        const float invN = 1.0f / (float)((long long)Bn * Hn * Wn);  // 1/2^25, exact
        out[0] = ((smem[0] + smem[1]) + (smem[2] + smem[3])) * invN;
    }
}

extern "C" void kernel_launch(void* const* d_in, const int* in_sizes, int n_in,
                              void* d_out, int out_size, void* d_ws, size_t ws_size,
                              hipStream_t stream)
{
    const float* pred = (const float*)d_in[0];
    const float* tgt  = (const float*)d_in[1];
    float* partial = (float*)d_ws;            // 8192 floats = 32 KB, fully
                                              // overwritten each call (poison-safe)
    bam_bce_rows<<<GRID1, 256, 0, stream>>>(pred, tgt, partial);
    bam_bce_reduce<<<1, 256, 0, stream>>>(partial, (float*)d_out);
}